// Round 8
// baseline (179.647 us; speedup 1.0000x reference)
//
#include <hip/hip_runtime.h>

// RWKV-4 WKV forward. B=16, T=1024, C=2048, fp32.
// T-split chunked scan, z-space formulation. Block = 16 waves x 64 channels
// (1024 threads -> 32 waves/CU, the HW max, vs 16 with 8-wave blocks);
// each 128-t segment = 16 waves x 8 t in registers (double-buffered).
// z_j = k_j - j*w folds decay into the index:
//   - exclusive prefix max M_j: pure v_max chain
//   - rescale factors cf/df: independent exps (off critical path)
//   - P/Q accumulators: pure fma chains
//   - y_j uses exact normalizer no = max3(o+jw, (j-1)w+M_j, u+k_j)
// One barrier per segment; running state double-buffered in LDS.

#define T_DIM 1024
#define CDIM  2048
#define CHUNK 8
#define WAVES 16
#define SEG   (WAVES * CHUNK)   // 128
#define NSEG  (T_DIM / SEG)     // 8
#define NEG_BIG -1e38f

__global__ __launch_bounds__(WAVES * 64, 8) void wkv_fwd_kernel(
    const float* __restrict__ w, const float* __restrict__ u,
    const float* __restrict__ kk, const float* __restrict__ vv,
    float* __restrict__ y)
{
    __shared__ float Tp[2][WAVES][64], Tq[2][WAVES][64], To[2][WAVES][64];
    __shared__ float Sp[2][64], Sq[2][64], So[2][64];

    const int lane = threadIdx.x & 63;
    const int wid  = threadIdx.x >> 6;
    const int c    = blockIdx.x * 64 + lane;
    const int b    = blockIdx.y;

    const float wc  = w[c];
    const float uc  = u[c];
    const float wCH = wc * (float)CHUNK;

    const size_t base = (size_t)b * T_DIM * CDIM + c;   // + t*CDIM
    const float* kp = kk + base;
    const float* vp = vv + base;
    float*       yp = y  + base;

    if (wid == 0) { Sp[0][lane] = 0.f; Sq[0][lane] = 0.f; So[0][lane] = NEG_BIG; }

    float k0[CHUNK], v0[CHUNK], k1[CHUNK], v1[CHUNK];

    // prologue: segment 0 -> buf0, segment 1 -> buf1 (coalesced wave loads)
    {
        const int t0 = wid * CHUNK;
#pragma unroll
        for (int j = 0; j < CHUNK; ++j) { k0[j] = kp[(size_t)(t0 + j) * CDIM];       v0[j] = vp[(size_t)(t0 + j) * CDIM]; }
#pragma unroll
        for (int j = 0; j < CHUNK; ++j) { k1[j] = kp[(size_t)(t0 + SEG + j) * CDIM]; v1[j] = vp[(size_t)(t0 + SEG + j) * CDIM]; }
    }
    __builtin_amdgcn_sched_barrier(0);

    auto body = [&](int s, float (&kc)[CHUNK], float (&vc)[CHUNK]) {
        const int sl = s & 1;

        // z-space precompute (independent exps; short max chain)
        float uk[CHUNK], hh[CHUNK], cf[CHUNK], df[CHUNK];
        float M = NEG_BIG;
#pragma unroll
        for (int j = 0; j < CHUNK; ++j) {
            const float zj = fmaf((float)(-j), wc, kc[j]);  // k_j - j*w
            uk[j] = uc + kc[j];
            const float dl = M - zj;
            cf[j] = __expf(fminf(dl, 0.f));                 // carry factor
            df[j] = __expf(fminf(-dl, 0.f));                // new-term factor
            hh[j] = fmaf((float)(j - 1), wc, M);            // (j-1)w + M_j
            M = fmaxf(M, zj);
        }

        // inclusive chunk totals (pure fma chains) -> publish transform
        float Pt = 0.f, Qt = 0.f;
#pragma unroll
        for (int j = 0; j < CHUNK; ++j) {
            Pt = fmaf(cf[j], Pt, df[j] * vc[j]);
            Qt = fmaf(cf[j], Qt, df[j]);
        }
        if (wid < WAVES - 1) {
            Tp[sl][wid][lane] = Pt;
            Tq[sl][wid][lane] = Qt;
            To[sl][wid][lane] = fmaf((float)(CHUNK - 1), wc, M);
        }
        __syncthreads();

        // compose S_in = S_run ∘ T_0 ∘ ... ∘ T_{wid-1}
        float p = Sp[sl][lane], q = Sq[sl][lane], o = So[sl][lane];
        for (int j = 0; j < wid; ++j) {       // wave-uniform trip count
            const float Oj = To[sl][j][lane];
            const float a  = o + wCH;
            const float d  = a - Oj;
            const float e  = __expf(-fabsf(d));
            const float sA = d >= 0.f ? 1.f : e;
            const float sB = d >= 0.f ? e : 1.f;
            p = fmaf(sA, p, sB * Tp[sl][j][lane]);
            q = fmaf(sA, q, sB * Tq[sl][j][lane]);
            o = fmaxf(a, Oj);
        }

        // y loop: exact per-step normalizer; exclusive accumulators rerun
        const int tbase = s * SEG + wid * CHUNK;
        float aP = 0.f, aQ = 0.f;
#pragma unroll
        for (int j = 0; j < CHUNK; ++j) {
            const float g   = fmaf((float)j, wc, o);         // o + j*w
            const float no  = fmaxf(fmaxf(g, hh[j]), uk[j]);
            const float ea  = __expf(g - no);
            const float eb  = __expf(hh[j] - no);
            const float ec  = __expf(uk[j] - no);
            const float num = fmaf(ea, p, fmaf(eb, aP, ec * vc[j]));
            const float den = fmaf(ea, q, fmaf(eb, aQ, ec));
            yp[(size_t)(tbase + j) * CDIM] = __fdividef(num, den);
            aP = fmaf(cf[j], aP, df[j] * vc[j]);
            aQ = fmaf(cf[j], aQ, df[j]);
        }

        // new running state: last wave composes its own transform on top
        if (wid == WAVES - 1) {
            const float Ot = fmaf((float)(CHUNK - 1), wc, M);
            const float a  = o + wCH;
            const float d  = a - Ot;
            const float e  = __expf(-fabsf(d));
            const float sA = d >= 0.f ? 1.f : e;
            const float sB = d >= 0.f ? e : 1.f;
            Sp[1 - sl][lane] = fmaf(sA, p, sB * Pt);
            Sq[1 - sl][lane] = fmaf(sA, q, sB * Qt);
            So[1 - sl][lane] = fmaxf(a, Ot);
        }

        // prefetch segment s+2 into the freed buffer
        if (s + 2 < NSEG) {
            const int tn = tbase + 2 * SEG;
#pragma unroll
            for (int j = 0; j < CHUNK; ++j) {
                kc[j] = kp[(size_t)(tn + j) * CDIM];
                vc[j] = vp[(size_t)(tn + j) * CDIM];
            }
        }
        __builtin_amdgcn_sched_barrier(0);
    };

#pragma unroll 1
    for (int s2 = 0; s2 < NSEG; s2 += 2) {
        body(s2,     k0, v0);
        body(s2 + 1, k1, v1);
    }
}

extern "C" void kernel_launch(void* const* d_in, const int* in_sizes, int n_in,
                              void* d_out, int out_size, void* d_ws, size_t ws_size,
                              hipStream_t stream) {
    // inputs: 0=B, 1=T, 2=C (scalars), 3=w[C], 4=u[C], 5=k[B*T*C], 6=v[B*T*C]
    const float* w = (const float*)d_in[3];
    const float* u = (const float*)d_in[4];
    const float* k = (const float*)d_in[5];
    const float* v = (const float*)d_in[6];
    float* y = (float*)d_out;

    const int B = in_sizes[5] / (T_DIM * CDIM);   // 16

    dim3 grid(CDIM / 64, B);
    dim3 block(WAVES * 64);
    wkv_fwd_kernel<<<grid, block, 0, stream>>>(w, u, k, v, y);
}

// Round 9
// 93.666 us; speedup vs baseline: 1.9179x; 1.9179x over previous
//
#include <hip/hip_runtime.h>

// RWKV-4 WKV forward. B=16, T=1024, C=2048, fp32.
// T-split chunked scan (z-space) + LDS-ring streaming:
//  - block = 8 waves x 64 channels; segment = 64 t = 8 waves x 8 t
//  - k/v stream through a 2-slot LDS ring via global_load_lds width=16
//    (1KB/request; each wave loads exactly its own 8 rows -> per-wave vmcnt)
//  - RAW s_barrier + lgkmcnt(0) only (no __syncthreads) so global loads
//    stay in flight across barriers; exact counted vmcnt gates
//  - y staged into the consumed k rows of the LDS slot, stored as 2x dwordx4
// Sync audit: T/S arrays ds_write -> lgkmcnt(0) -> s_barrier -> readers.
// Ring slot s&1: my reads (z-phase, y-stage) precede my end-issue of seg s+2
// (same slot) in per-wave program order; other waves never touch my rows.

#define T_DIM 1024
#define CDIM  2048
#define CHUNK 8
#define WAVES 8
#define SEG   (WAVES * CHUNK)   // 64
#define NSEG  (T_DIM / SEG)     // 16
#define NEG_BIG -1e38f

typedef const __attribute__((address_space(1))) float* gp_t;
typedef __attribute__((address_space(3))) float* lp_t;

__global__ __launch_bounds__(WAVES * 64, 4) void wkv_fwd_kernel(
    const float* __restrict__ w, const float* __restrict__ u,
    const float* __restrict__ kk, const float* __restrict__ vv,
    float* __restrict__ y)
{
    __shared__ __align__(16) float lk[2][SEG][64];   // 32 KB
    __shared__ __align__(16) float lv[2][SEG][64];   // 32 KB
    __shared__ float Tp[WAVES][64], Tq[WAVES][64], To[WAVES][64];  // 6 KB
    __shared__ float Sp[2][64], Sq[2][64], So[2][64];              // 1.5 KB

    const int lane = threadIdx.x & 63;
    const int wid  = threadIdx.x >> 6;
    const int b    = blockIdx.y;
    const int c0   = blockIdx.x * 64;

    const float wc  = w[c0 + lane];
    const float uc  = u[c0 + lane];
    const float wCH = wc * (float)CHUNK;

    const size_t sbase = (size_t)b * T_DIM * CDIM + c0;  // slab base (t=0)
    const int rl = lane >> 4;           // row within 4-row group
    const int cl = (lane & 15) * 4;     // col dword
    const float* kgl = kk + sbase + (size_t)rl * CDIM + cl;
    const float* vgl = vv + sbase + (size_t)rl * CDIM + cl;
    float*       ygl = y  + sbase + cl;

    if (wid == 0) { Sp[0][lane] = 0.f; Sq[0][lane] = 0.f; So[0][lane] = NEG_BIG; }

    // issue one segment's worth of this wave's rows: 4 x width-16 gload_lds
    auto issue_seg = [&](int s) {
        const int sl = s & 1;
        const int trow = s * SEG + wid * CHUNK;
#pragma unroll
        for (int g = 0; g < 2; ++g) {
            const size_t go = (size_t)(trow + 4 * g) * CDIM;
            __builtin_amdgcn_global_load_lds((gp_t)(kgl + go),
                (lp_t)&lk[sl][wid * CHUNK + 4 * g][0], 16, 0, 0);
            __builtin_amdgcn_global_load_lds((gp_t)(vgl + go),
                (lp_t)&lv[sl][wid * CHUNK + 4 * g][0], 16, 0, 0);
        }
    };

    issue_seg(0);
    issue_seg(1);

#pragma unroll 1
    for (int s = 0; s < NSEG; ++s) {
        const int sl = s & 1;

        // wait for MY segment-s loads (exact FIFO count of newer ops:
        // s==0: seg1's 4; 1..NSEG-2: 2 stores + 4 loads; NSEG-1: 2 stores)
        if (s == 0)            asm volatile("s_waitcnt vmcnt(4)" ::: "memory");
        else if (s == NSEG-1)  asm volatile("s_waitcnt vmcnt(2)" ::: "memory");
        else                   asm volatile("s_waitcnt vmcnt(6)" ::: "memory");
        __builtin_amdgcn_sched_barrier(0);

        // z-space precompute from LDS slot sl
        float uk[CHUNK], hh[CHUNK], cf[CHUNK], df[CHUNK], vc[CHUNK];
        float M = NEG_BIG;
#pragma unroll
        for (int j = 0; j < CHUNK; ++j) {
            const float kt = lk[sl][wid * CHUNK + j][lane];
            vc[j] = lv[sl][wid * CHUNK + j][lane];
            const float zj = fmaf((float)(-j), wc, kt);   // k_j - j*w
            uk[j] = uc + kt;
            const float dl = M - zj;
            cf[j] = __expf(fminf(dl, 0.f));
            df[j] = __expf(fminf(-dl, 0.f));
            hh[j] = fmaf((float)(j - 1), wc, M);
            M = fmaxf(M, zj);
        }
        float Pt = 0.f, Qt = 0.f;
#pragma unroll
        for (int j = 0; j < CHUNK; ++j) {
            Pt = fmaf(cf[j], Pt, df[j] * vc[j]);
            Qt = fmaf(cf[j], Qt, df[j]);
        }
        if (wid < WAVES - 1) {
            Tp[wid][lane] = Pt; Tq[wid][lane] = Qt;
            To[wid][lane] = fmaf((float)(CHUNK - 1), wc, M);
        }

        // barrier A: T (and S from prev segment) visible; vmem stays in flight
        asm volatile("s_waitcnt lgkmcnt(0)" ::: "memory");
        __builtin_amdgcn_s_barrier();

        // compose S_in = S_run ∘ T_0 ∘ ... ∘ T_{wid-1}
        float p = Sp[sl][lane], q = Sq[sl][lane], o = So[sl][lane];
        for (int j = 0; j < wid; ++j) {       // wave-uniform trip count
            const float Oj = To[j][lane];
            const float a  = o + wCH;
            const float d  = a - Oj;
            const float e  = __expf(-fabsf(d));
            const float sA = d >= 0.f ? 1.f : e;
            const float sB = d >= 0.f ? e : 1.f;
            p = fmaf(sA, p, sB * Tp[j][lane]);
            q = fmaf(sA, q, sB * Tq[j][lane]);
            o = fmaxf(a, Oj);
        }

        // new running state (uses compose result + own totals only)
        if (wid == WAVES - 1) {
            const float Ot = fmaf((float)(CHUNK - 1), wc, M);
            const float a  = o + wCH;
            const float d  = a - Ot;
            const float e  = __expf(-fabsf(d));
            const float sA = d >= 0.f ? 1.f : e;
            const float sB = d >= 0.f ? e : 1.f;
            Sp[1 - sl][lane] = fmaf(sA, p, sB * Pt);
            Sq[1 - sl][lane] = fmaf(sA, q, sB * Qt);
            So[1 - sl][lane] = fmaxf(a, Ot);
        }

        // barrier B: all compose reads of T done -> T writable next segment
        asm volatile("s_waitcnt lgkmcnt(0)" ::: "memory");
        __builtin_amdgcn_s_barrier();

        // y loop: exact per-step normalizer; stage y into consumed k rows
        const int tb = s * SEG + wid * CHUNK;
        float aP = 0.f, aQ = 0.f;
#pragma unroll
        for (int j = 0; j < CHUNK; ++j) {
            const float g   = fmaf((float)j, wc, o);
            const float no  = fmaxf(fmaxf(g, hh[j]), uk[j]);
            const float ea  = __expf(g - no);
            const float eb  = __expf(hh[j] - no);
            const float ec  = __expf(uk[j] - no);
            const float num = fmaf(ea, p, fmaf(eb, aP, ec * vc[j]));
            const float den = fmaf(ea, q, fmaf(eb, aQ, ec));
            lk[sl][wid * CHUNK + j][lane] = __fdividef(num, den);
            aP = fmaf(cf[j], aP, df[j] * vc[j]);
            aQ = fmaf(cf[j], aQ, df[j]);
        }

        // y out: 2 coalesced dwordx4 stores (2 vmcnt items/segment)
#pragma unroll
        for (int g = 0; g < 2; ++g) {
            const int r = 4 * g + rl;
            const float4 yv = *reinterpret_cast<const float4*>(
                &lk[sl][wid * CHUNK + r][cl]);
            *reinterpret_cast<float4*>(ygl + (size_t)(tb + r) * CDIM) = yv;
        }

        // end-issue segment s+2 into slot sl (all my slot-sl accesses done)
        if (s + 2 < NSEG) {
            asm volatile("s_waitcnt lgkmcnt(0)" ::: "memory");
            __builtin_amdgcn_sched_barrier(0);
            issue_seg(s + 2);
        }
    }
}

extern "C" void kernel_launch(void* const* d_in, const int* in_sizes, int n_in,
                              void* d_out, int out_size, void* d_ws, size_t ws_size,
                              hipStream_t stream) {
    // inputs: 0=B, 1=T, 2=C (scalars), 3=w[C], 4=u[C], 5=k[B*T*C], 6=v[B*T*C]
    const float* w = (const float*)d_in[3];
    const float* u = (const float*)d_in[4];
    const float* k = (const float*)d_in[5];
    const float* v = (const float*)d_in[6];
    float* y = (float*)d_out;

    const int B = in_sizes[5] / (T_DIM * CDIM);   // 16

    dim3 grid(CDIM / 64, B);
    dim3 block(WAVES * 64);
    wkv_fwd_kernel<<<grid, block, 0, stream>>>(w, u, k, v, y);
}